// Round 7
// baseline (482.121 us; speedup 1.0000x reference)
//
#include <hip/hip_runtime.h>
#include <cstdint>
#include <cstddef>

// ---------------------------------------------------------------------------
// GCN forward:  softmax( (A_hat relu(A_hat (X W1 + b1) W2)) Wl + bl )
// conv1 reordered: aggregate features (F=512) first, GEMM1 epilogue adds
// rowsum*b1. conv2: project (8192->4096) then aggregate.
// GEMM (R7): 256x256 tile, BK=64, 8 waves (2M x 4N), 2-buffer LDS (128KB).
// COMPILER-SCHEDULED tile body (m141 lesson: phase pinning defeats the
// scheduler): per K-tile only 2 barriers -
//   vmcnt(8) ; barrier ; {24 ds_read + 64 MFMA, freely scheduled} ;
//   lgkmcnt(0) ; barrier ; stage tile t+2 into this tile's buffer.
// Counted vmcnt: stage(t+2) issued at end of tile t => 16 loads in flight;
// vmcnt(8) at tile t+1 start waits only tile t+1's loads. Drain to 0 only
// at the last tile. T2 XOR swizzle (both sides), bijective XCD swizzle.
// agg2: 512-col stripes pinned to XCDs via bid%8 -> gather from L2.
// ---------------------------------------------------------------------------

using bf8   = __attribute__((ext_vector_type(8))) short;   // 8 bf16 (4 VGPR)
using s4    = __attribute__((ext_vector_type(4))) short;
using f32x4 = __attribute__((ext_vector_type(4))) float;

static __device__ __forceinline__ unsigned short f2bf(float f) {
    union { float f; uint32_t u; } v; v.f = f;
    uint32_t r = (v.u + 0x7FFFu + ((v.u >> 16) & 1u)) >> 16;   // RNE
    return (unsigned short)r;
}
static __device__ __forceinline__ float bf2f(unsigned short b) {
    union { uint32_t u; float f; } v; v.u = ((uint32_t)b) << 16;
    return v.f;
}

static __device__ __forceinline__ void gload16(const short* g, short* l) {
    __builtin_amdgcn_global_load_lds(
        (const __attribute__((address_space(1))) unsigned int*)g,
        (__attribute__((address_space(3))) unsigned int*)l,
        16, 0, 0);
}

// ---------------- prep kernels ----------------

__global__ void k_zero(float* a, float* b, int* c, int n) {
    int i = blockIdx.x * blockDim.x + threadIdx.x;
    if (i < n) { a[i] = 0.f; b[i] = 0.f; c[i] = 0; }
}

__global__ void k_count(const int* __restrict__ src, const int* __restrict__ dst,
                        float* deg_out, float* deg_in, int E) {
    int e = blockIdx.x * blockDim.x + threadIdx.x;
    if (e < E) {
        atomicAdd(&deg_out[src[e]], 1.f);
        atomicAdd(&deg_in[dst[e]], 1.f);
    }
}

__global__ void k_inv(const float* deg_out, const float* deg_in,
                      float* inv_out, float* inv_in, int n) {
    int i = blockIdx.x * blockDim.x + threadIdx.x;
    if (i < n) {
        inv_out[i] = rsqrtf(fmaxf(deg_out[i], 1.f));
        inv_in[i]  = rsqrtf(fmaxf(deg_in[i], 1.f));
    }
}

__global__ void k_scan(const float* __restrict__ deg_in, int* __restrict__ row_off) {
    __shared__ int part[1024];
    const int t = threadIdx.x;
    int v0 = (int)deg_in[t*4+0], v1 = (int)deg_in[t*4+1],
        v2 = (int)deg_in[t*4+2], v3 = (int)deg_in[t*4+3];
    part[t] = v0 + v1 + v2 + v3;
    __syncthreads();
    for (int off = 1; off < 1024; off <<= 1) {
        int x = (t >= off) ? part[t - off] : 0;
        __syncthreads();
        part[t] += x;
        __syncthreads();
    }
    int run = (t == 0) ? 0 : part[t-1];
    row_off[t*4+0] = run; run += v0;
    row_off[t*4+1] = run; run += v1;
    row_off[t*4+2] = run; run += v2;
    row_off[t*4+3] = run; run += v3;
    if (t == 1023) row_off[4096] = run;
}

__global__ void k_fill(const int* __restrict__ src, const int* __restrict__ dst,
                       const int* __restrict__ row_off, int* cursor,
                       int* __restrict__ esrc, int E) {
    int e = blockIdx.x * blockDim.x + threadIdx.x;
    if (e < E) {
        int d = dst[e];
        int p = atomicAdd(&cursor[d], 1);
        esrc[row_off[d] + p] = src[e];
    }
}

__global__ void k_rowsum(const int* __restrict__ row_off, const int* __restrict__ esrc,
                         const float* __restrict__ inv_out, const float* __restrict__ inv_in,
                         float* __restrict__ rowsum) {
    const int node = blockIdx.x, lane = threadIdx.x;
    const int beg = row_off[node], end = row_off[node + 1];
    float s = 0.f;
    for (int p = beg + lane; p < end; p += 64) s += inv_out[esrc[p]];
    #pragma unroll
    for (int off = 32; off; off >>= 1) s += __shfl_down(s, off, 64);
    if (lane == 0) rowsum[node] = s * inv_in[node];
}

__global__ void k_cvt_scale(const float* __restrict__ in, const float* __restrict__ sc,
                            short* __restrict__ out, int n4, int f4) {
    int i = blockIdx.x * blockDim.x + threadIdx.x;
    if (i < n4) {
        const float s = sc[i / f4];
        float4 v = reinterpret_cast<const float4*>(in)[i];
        s4 o;
        o[0] = (short)f2bf(v.x * s); o[1] = (short)f2bf(v.y * s);
        o[2] = (short)f2bf(v.z * s); o[3] = (short)f2bf(v.w * s);
        reinterpret_cast<s4*>(out)[i] = o;
    }
}

// fp32 [R][C] -> bf16 [C][R]; 64(r)x32(c) tile, block (32,8), ushort2 writes
__global__ void k_tr2(const float* __restrict__ in, short* __restrict__ out, int R, int C) {
    __shared__ float tile[64][33];
    const int bc = blockIdx.x * 32, br = blockIdx.y * 64;
    const int tx = threadIdx.x, ty = threadIdx.y;
    #pragma unroll
    for (int dy = 0; dy < 64; dy += 8)
        tile[ty + dy][tx] = in[(size_t)(br + ty + dy) * C + bc + tx];
    __syncthreads();
    #pragma unroll
    for (int dy = 0; dy < 32; dy += 8) {
        const int oy = ty + dy;
        ushort2 o;
        o.x = f2bf(tile[tx * 2][oy]);
        o.y = f2bf(tile[tx * 2 + 1][oy]);
        *reinterpret_cast<ushort2*>(&out[(size_t)(bc + oy) * R + br + tx * 2]) = o;
    }
}

// ---------------- bf16 MFMA GEMM, compiler-scheduled 2-barrier pipeline ----------------
// C[M][N] = A[M][K] * Bt^T; A row-major, Bt = B^T row-major [N][K], all bf16.
// EPI==1: out = acc + rs[row]*bias[col]; EPI==2: out = acc * rs[row].
// Tile 256x256, BK=64. 8 waves = 2M x 4N, wave tile 128x64.
// LDS: 2 buffers x (A[256][64] + B[256][64]) = 128KB; tile t in buf[t&1].
// Stage of tile t+2 targets buf[t&1]: issued only after lgkmcnt(0)+barrier
// at end of tile t (all waves' reads of that buffer complete). In flight
// after issue: 16 loads; vmcnt(8) at tile t+1 start waits t+1's 8 only.
// Tile body has NO internal barriers or sched pins: 24 ds_read_b128 + 64
// MFMA, compiler-scheduled (counted lgkm interleave). Swizzle: source chunk
// cs = cq ^ (row&7), ds_read applies same XOR (conflict-free, verified R4+).
// Requires nt >= 2 and M%256==N%256==K%64==0; grid nwg%8==0 (XCD swizzle).
template<int EPI>
__global__ __launch_bounds__(512, 2)
void gemm8p(const short* __restrict__ A, const short* __restrict__ Bt,
            short* __restrict__ C,
            const float* __restrict__ bias, const float* __restrict__ rs,
            int M, int N, int K)
{
    constexpr int USZ  = 4096;            // shorts per 64-row x 64-short unit
    constexpr int BOFF = 4 * USZ;         // B region offset within buffer (16384)
    constexpr int BUF  = 8 * USZ;         // shorts per buffer (32768 = 64KB)
    __shared__ __align__(16) short lds[2 * BUF];   // 128 KB
    const int tid  = threadIdx.x;
    const int wid  = tid >> 6, lane = tid & 63;
    const int wm   = wid >> 2;            // 0..1  (M wave index)
    const int wn   = wid & 3;             // 0..3  (N wave index)
    const int fr   = lane & 15;
    const int kq   = lane >> 4;           // 0..3
    const int nt   = K >> 6;

    // bijective XCD-chunk swizzle (nwg % 8 == 0)
    const int gx  = gridDim.x;
    const int nwg = gx * gridDim.y;
    int bid = blockIdx.y * gx + blockIdx.x;
    bid = (bid & 7) * (nwg >> 3) + (bid >> 3);
    const int tm = (bid / gx) * 256;
    const int tn = (bid % gx) * 256;

    // ---- staging addressing (per thread: 1 gload16 per 8KB unit) ----
    const int srow = tid >> 3;            // 0..63 row within unit
    const int scq  = tid & 7;             // linear 16B-chunk within row
    const int scs  = scq ^ (srow & 7);    // pre-swizzled source chunk
    const short* gA = A  + (size_t)(tm + srow) * K + scs * 8;
    const short* gB = Bt + (size_t)(tn + srow) * K + scs * 8;
    short* const ldst = lds + tid * 8;    // + bufoff + unit*USZ (shorts)

    // ---- fragment read offsets (shorts, lane-constant) ----
    const int cx0 = (0 * 4 + kq) ^ (fr & 7);
    const int cx1 = (1 * 4 + kq) ^ (fr & 7);
    int aoff[8][2], boff[4][2];
    #pragma unroll
    for (int mi = 0; mi < 8; ++mi) {
        const int r = wm * 128 + mi * 16 + fr;
        aoff[mi][0] = r * 64 + cx0 * 8;
        aoff[mi][1] = r * 64 + cx1 * 8;
    }
    #pragma unroll
    for (int n = 0; n < 4; ++n) {
        const int r = wn * 64 + n * 16 + fr;
        boff[n][0] = BOFF + r * 64 + cx0 * 8;
        boff[n][1] = BOFF + r * 64 + cx1 * 8;
    }

    f32x4 acc[8][4];
    #pragma unroll
    for (int mi = 0; mi < 8; ++mi)
        #pragma unroll
        for (int n = 0; n < 4; ++n)
            acc[mi][n] = (f32x4){0.f, 0.f, 0.f, 0.f};

    // ---- prologue: stage tile 0 -> buf0, tile 1 -> buf1 (16 loads in flight) ----
    #pragma unroll
    for (int u = 0; u < 4; ++u) gload16(gA + (size_t)u * 64 * K, ldst + u * USZ);
    #pragma unroll
    for (int v = 0; v < 4; ++v) gload16(gB + (size_t)v * 64 * K, ldst + BOFF + v * USZ);
    #pragma unroll
    for (int u = 0; u < 4; ++u) gload16(gA + (size_t)u * 64 * K + 64, ldst + BUF + u * USZ);
    #pragma unroll
    for (int v = 0; v < 4; ++v) gload16(gB + (size_t)v * 64 * K + 64, ldst + BUF + BOFF + v * USZ);

    for (int t = 0; t < nt; ++t) {
        const int cc = (t & 1) * BUF;     // compute buffer == stage target for t+2

        // tile t's loads have landed (counted: t+1's 8 stay in flight)
        if (t + 1 < nt) { asm volatile("s_waitcnt vmcnt(8)" ::: "memory"); }
        else            { asm volatile("s_waitcnt vmcnt(0)" ::: "memory"); }
        __builtin_amdgcn_sched_barrier(0);
        __builtin_amdgcn_s_barrier();

        // ---- tile body: compiler-scheduled reads + MFMAs (no pins) ----
        #pragma unroll
        for (int s = 0; s < 2; ++s) {
            bf8 b[4], a[8];
            #pragma unroll
            for (int n = 0; n < 4; ++n)
                b[n] = *reinterpret_cast<const bf8*>(lds + cc + boff[n][s]);
            #pragma unroll
            for (int mi = 0; mi < 8; ++mi)
                a[mi] = *reinterpret_cast<const bf8*>(lds + cc + aoff[mi][s]);
            #pragma unroll
            for (int mi = 0; mi < 8; ++mi)
                #pragma unroll
                for (int n = 0; n < 4; ++n)
                    acc[mi][n] = __builtin_amdgcn_mfma_f32_16x16x32_bf16(a[mi], b[n], acc[mi][n], 0, 0, 0);
        }

        // all my reads of buf[t&1] done; join workgroup; then overwrite it
        asm volatile("s_waitcnt lgkmcnt(0)" ::: "memory");
        __builtin_amdgcn_sched_barrier(0);
        __builtin_amdgcn_s_barrier();
        if (t + 2 < nt) {
            const size_t kf = (size_t)(t + 2) * 64;
            #pragma unroll
            for (int u = 0; u < 4; ++u)
                gload16(gA + (size_t)u * 64 * K + kf, ldst + cc + u * USZ);
            #pragma unroll
            for (int v = 0; v < 4; ++v)
                gload16(gB + (size_t)v * 64 * K + kf, ldst + cc + BOFF + v * USZ);
        }
    }

    // ---- epilogue: C/D layout col = lane&15, row = (lane>>4)*4 + reg ----
    const int rb = kq * 4;
    #pragma unroll
    for (int mi = 0; mi < 8; ++mi) {
        #pragma unroll
        for (int n = 0; n < 4; ++n) {
            const int col = tn + wn * 64 + n * 16 + fr;
            const float bcol = (EPI == 1) ? bias[col] : 0.f;
            #pragma unroll
            for (int j = 0; j < 4; ++j) {
                const int row = tm + wm * 128 + mi * 16 + rb + j;
                float v = acc[mi][n][j];
                if (EPI == 1) v += rs[row] * bcol;
                else          v *= rs[row];
                C[(size_t)row * N + col] = (short)f2bf(v);
            }
        }
    }
}

// ---------------- CSR aggregation, L2-striped ----------------
// Y[i] = inv_in[i] * sum_{e: dst=i} X[src[e]].  512-col stripe (4 MB of X at
// F=4096) pinned to one XCD: linear bid % 8 == blockIdx.x == stripe, and
// dispatch round-robins linear bid across XCDs. 64-thread blocks.
template<int RELU>
__global__ __launch_bounds__(64)
void agg_strip(const short* __restrict__ X, short* __restrict__ Y,
               const int* __restrict__ row_off, const int* __restrict__ esrc,
               const float* __restrict__ inv_in, int F)
{
    const int node = blockIdx.y;
    const int c0 = blockIdx.x * 512 + threadIdx.x * 8;
    float acc[8];
    #pragma unroll
    for (int j = 0; j < 8; ++j) acc[j] = 0.f;

    const int beg = row_off[node], end = row_off[node + 1];
    int p = beg;
    for (; p + 3 < end; p += 4) {
        const int s0 = esrc[p], s1 = esrc[p + 1], s2 = esrc[p + 2], s3 = esrc[p + 3];
        bf8 x0 = *reinterpret_cast<const bf8*>(X + (size_t)s0 * F + c0);
        bf8 x1 = *reinterpret_cast<const bf8*>(X + (size_t)s1 * F + c0);
        bf8 x2 = *reinterpret_cast<const bf8*>(X + (size_t)s2 * F + c0);
        bf8 x3 = *reinterpret_cast<const bf8*>(X + (size_t)s3 * F + c0);
        #pragma unroll
        for (int j = 0; j < 8; ++j)
            acc[j] += (bf2f((unsigned short)x0[j]) + bf2f((unsigned short)x1[j]))
                    + (bf2f((unsigned short)x2[j]) + bf2f((unsigned short)x3[j]));
    }
    for (; p < end; ++p) {
        const int s0 = esrc[p];
        bf8 x0 = *reinterpret_cast<const bf8*>(X + (size_t)s0 * F + c0);
        #pragma unroll
        for (int j = 0; j < 8; ++j) acc[j] += bf2f((unsigned short)x0[j]);
    }
    const float sc = inv_in[node];
    bf8 o;
    #pragma unroll
    for (int j = 0; j < 8; ++j) {
        float v = acc[j] * sc;
        if (RELU) v = fmaxf(v, 0.f);
        o[j] = (short)f2bf(v);
    }
    *reinterpret_cast<bf8*>(Y + (size_t)node * F + c0) = o;
}

// ---------------- head: logits = H[4096] . Wl[4096][16] + bl; softmax ----------------
__global__ __launch_bounds__(256)
void k_head(const short* __restrict__ H, const float* __restrict__ Wl,
            const float* __restrict__ bl, float* __restrict__ out)
{
    const int row = blockIdx.x;
    const int tid = threadIdx.x;
    float acc[16];
    #pragma unroll
    for (int c = 0; c < 16; ++c) acc[c] = 0.f;

    for (int k = tid; k < 4096; k += 256) {
        const float x = bf2f((unsigned short)H[(size_t)row * 4096 + k]);
        const float4* w = reinterpret_cast<const float4*>(Wl + (size_t)k * 16);
        float4 w0 = w[0], w1 = w[1], w2 = w[2], w3 = w[3];
        acc[0]  += x * w0.x; acc[1]  += x * w0.y; acc[2]  += x * w0.z; acc[3]  += x * w0.w;
        acc[4]  += x * w1.x; acc[5]  += x * w1.y; acc[6]  += x * w1.z; acc[7]  += x * w1.w;
        acc[8]  += x * w2.x; acc[9]  += x * w2.y; acc[10] += x * w2.z; acc[11] += x * w2.w;
        acc[12] += x * w3.x; acc[13] += x * w3.y; acc[14] += x * w3.z; acc[15] += x * w3.w;
    }
    #pragma unroll
    for (int c = 0; c < 16; ++c)
        for (int off = 32; off; off >>= 1)
            acc[c] += __shfl_down(acc[c], off, 64);

    __shared__ float sm[16][4];
    const int wid = tid >> 6, lane = tid & 63;
    if (lane == 0) {
        #pragma unroll
        for (int c = 0; c < 16; ++c) sm[c][wid] = acc[c];
    }
    __syncthreads();
    if (tid < 16) {
        float l = sm[tid][0] + sm[tid][1] + sm[tid][2] + sm[tid][3] + bl[tid];
        float mx = l;
        #pragma unroll
        for (int off = 1; off < 16; off <<= 1) mx = fmaxf(mx, __shfl_xor(mx, off, 16));
        float e = expf(l - mx);
        float s = e;
        #pragma unroll
        for (int off = 1; off < 16; off <<= 1) s += __shfl_xor(s, off, 16);
        out[(size_t)row * 16 + tid] = e / s;
    }
}

// ---------------- launch ----------------

extern "C" void kernel_launch(void* const* d_in, const int* in_sizes, int n_in,
                              void* d_out, int out_size, void* d_ws, size_t ws_size,
                              hipStream_t stream)
{
    const float* features = (const float*)d_in[0];
    const float* W1       = (const float*)d_in[1];
    const float* b1       = (const float*)d_in[2];
    const float* W2       = (const float*)d_in[3];
    const float* Wl       = (const float*)d_in[4];
    const float* bl       = (const float*)d_in[5];
    const int*   src      = (const int*)d_in[6];
    const int*   dst      = (const int*)d_in[7];
    float* out = (float*)d_out;

    const int N = 4096, IN = 512, H = 8192;
    const int E = in_sizes[6];

    char* ws = (char*)d_ws;
    size_t o = 0;
    auto alloc = [&](size_t bytes) -> char* {
        char* p = ws + o;
        o = (o + bytes + 255) & ~(size_t)255;
        return p;
    };
    short* W2t   = (short*)alloc((size_t)N * H * 2);     // 64 MB  W2^T bf16 [4096][8192]
    short* h1    = (short*)alloc((size_t)N * H * 2);     // 64 MB  conv1 out bf16 [4096][8192]
    short* x2s   = (short*)alloc((size_t)N * N * 2);     // 32 MB  (h1 W2)*inv_out bf16
    short* featb = (short*)alloc((size_t)N * IN * 2);    // 4 MB   features*inv_out bf16
    short* aggF  = (short*)alloc((size_t)N * IN * 2);    // 4 MB   A_hat X bf16
    short* W1t   = (short*)alloc((size_t)H * IN * 2);    // 8 MB   W1^T bf16 [8192][512]
    float* deg_out = (float*)alloc(N * 4);
    float* deg_in  = (float*)alloc(N * 4);
    float* inv_out = (float*)alloc(N * 4);
    float* inv_in  = (float*)alloc(N * 4);
    float* rowsum  = (float*)alloc(N * 4);
    int*   cursor  = (int*)alloc(N * 4);
    int*   row_off = (int*)alloc((N + 1) * 4);
    int*   esrc    = (int*)alloc((size_t)E * 4);
    short* h2 = h1;   // alias: h1 dead after GEMM2, h2 written by agg2

    // graph prep
    k_zero <<<(N + 255) / 256, 256, 0, stream>>>(deg_out, deg_in, cursor, N);
    k_count<<<(E + 255) / 256, 256, 0, stream>>>(src, dst, deg_out, deg_in, E);
    k_inv  <<<(N + 255) / 256, 256, 0, stream>>>(deg_out, deg_in, inv_out, inv_in, N);
    k_scan <<<1, 1024, 0, stream>>>(deg_in, row_off);
    k_fill <<<(E + 255) / 256, 256, 0, stream>>>(src, dst, row_off, cursor, esrc, E);
    k_rowsum<<<N, 64, 0, stream>>>(row_off, esrc, inv_out, inv_in, rowsum);

    // operand conversion
    k_cvt_scale<<<(N * IN / 4 + 255) / 256, 256, 0, stream>>>(features, inv_out, featb,
                                                              N * IN / 4, IN / 4);
    k_tr2<<<dim3(H / 32, IN / 64), dim3(32, 8), 0, stream>>>(W1, W1t, IN, H);
    k_tr2<<<dim3(N / 32, H / 64), dim3(32, 8), 0, stream>>>(W2, W2t, H, N);

    // conv1: aggregate features first (F=512), then GEMM1 with rowsum*b1 epilogue
    agg_strip<0><<<dim3(1, N), 64, 0, stream>>>(featb, aggF, row_off, esrc, inv_in, IN);
    gemm8p<1><<<dim3(H / 256, N / 256), 512, 0, stream>>>(aggF, W1t, h1, b1, rowsum, N, H, IN);

    // conv2: project first, then aggregate (L2-striped: stripe = bid%8 = XCD)
    gemm8p<2><<<dim3(N / 256, N / 256), 512, 0, stream>>>(h1, W2t, x2s, nullptr, inv_out, N, N, H);
    agg_strip<1><<<dim3(N / 512, N), 64, 0, stream>>>(x2s, h2, row_off, esrc, inv_in, N);

    // head + softmax
    k_head<<<N, 256, 0, stream>>>(h2, Wl, bl, out);
}